// Round 14
// baseline (128.304 us; speedup 1.0000x reference)
//
#include <hip/hip_runtime.h>

#define HW 50176            // 224*224
#define HW4 12544           // HW/4 (uint2-of-4xf16 / float4 units per frame)
#define TT 64
#define NBW 392             // part width: 8 b × 49 hwb (one t-chunk's blocks)
#define SUMW 0.9999f        // 0.2989+0.587+0.114

__device__ __forceinline__ float gelu_erf(float x) {
    return 0.5f * x * (1.0f + erff(0.70710678f * x));
}
__device__ __forceinline__ float fast_rcp(float v) {
    float r; asm("v_rcp_f32 %0, %1" : "=v"(r) : "v"(v)); return r;
}
__device__ __forceinline__ float gelu_fast(float x) {
    // tanh-form gelu; max |err| ~3e-3 vs erf (cancels through normalize)
    float x2 = x * x;
    float e = exp2f(-x * fmaf(0.1029433f, x2, 2.3022078f));
    return x * fast_rcp(1.0f + e);
}
__device__ __forceinline__ unsigned encf(float f) {
    unsigned u = __float_as_uint(f);
    return (u & 0x80000000u) ? ~u : (u | 0x80000000u);
}
__device__ __forceinline__ float decf(unsigned u) {
    unsigned b = (u & 0x80000000u) ? (u ^ 0x80000000u) : ~u;
    return __uint_as_float(b);
}
__device__ __forceinline__ unsigned pk_min_f16(unsigned a, unsigned b) {
    unsigned r; asm("v_pk_min_f16 %0, %1, %2" : "=v"(r) : "v"(a), "v"(b)); return r;
}
__device__ __forceinline__ unsigned pack2(float lo, float hi) {
    auto p = __builtin_amdgcn_cvt_pkrtz(lo, hi);
    return __builtin_bit_cast(unsigned, p);
}
__device__ __forceinline__ unsigned pk2(float r) { return pack2(r, -r); }   // (r,-r)
__device__ __forceinline__ unsigned mm4(float4 r) {
    return pk_min_f16(pk_min_f16(pk2(r.x), pk2(r.y)), pk_min_f16(pk2(r.z), pk2(r.w)));
}
__device__ __forceinline__ float4 re_full4(float4 w0, float4 w1, float4 w3, float4 w4) {
    float4 r;
    r.x = fmaf(4.f, w4.x - w0.x, 2.f * (w3.x - w1.x));
    r.y = fmaf(4.f, w4.y - w0.y, 2.f * (w3.y - w1.y));
    r.z = fmaf(4.f, w4.z - w0.z, 2.f * (w3.z - w1.z));
    r.w = fmaf(4.f, w4.w - w0.w, 2.f * (w3.w - w1.w));
    return r;
}
__device__ __forceinline__ uint2 gs4(float4 ra, float4 rb, float4 rc) {
    float gx = fmaf(0.114f, gelu_fast(rc.x), fmaf(0.587f, gelu_fast(rb.x), 0.2989f * gelu_fast(ra.x)));
    float gy = fmaf(0.114f, gelu_fast(rc.y), fmaf(0.587f, gelu_fast(rb.y), 0.2989f * gelu_fast(ra.y)));
    float gz = fmaf(0.114f, gelu_fast(rc.z), fmaf(0.587f, gelu_fast(rb.z), 0.2989f * gelu_fast(ra.z)));
    float gw = fmaf(0.114f, gelu_fast(rc.w), fmaf(0.587f, gelu_fast(rb.w), 0.2989f * gelu_fast(ra.w)));
    return make_uint2(pack2(gx, gy), pack2(gz, gw));
}

// Pass 1: 4 px/thread (float4), 2 t-chunks of 32 windows. Per-block DRAM visit is
// 4 KB per (frame,channel) — 4-8x the row locality of prior rounds. Flush/partial
// machinery identical to round 11/13.
template<bool WGS>
__global__ __launch_bounds__(256, 4) void k_pass1(const float* __restrict__ x,
                                                  unsigned* __restrict__ part,
                                                  uint2* __restrict__ gs) {
    __shared__ unsigned smin[32], smax[32];
    const int tid = threadIdx.x;
    if (tid < 32) smin[tid] = 0xFFFFFFFFu;
    else if (tid < 64) smax[tid - 32] = 0u;
    __syncthreads();

    const int bid = blockIdx.x;            // < 784 = 2 tc × 392
    const int tc  = bid >= NBW;
    const int sb  = tc ? bid - NBW : bid;  // 0..391
    const int b   = sb / 49;
    const int hwb = sb - b * 49;
    const int t0  = tc * 32;
    const int hw  = (hwb * 256 + tid) * 4;
    const float* xa = x + ((size_t)(b * 3 + 0) * TT + t0) * (size_t)HW + hw;
    const float* xb = x + ((size_t)(b * 3 + 1) * TT + t0) * (size_t)HW + hw;
    const float* xc = x + ((size_t)(b * 3 + 2) * TT + t0) * (size_t)HW + hw;
    uint2* gp = gs + ((size_t)b * TT + t0) * (size_t)HW4 + (hwb * 256 + tid);

    const int lane = tid & 63;
    unsigned keep = 0x7BFF7BFFu;           // lanes 0..31 end holding window t0+lane

    // frames (rel) r..r+4 in slots, pa = r+5; pointers -> r+6
    float4 a0 = *(const float4*)xa, b0 = *(const float4*)xb, c0 = *(const float4*)xc;
    float4 a1 = *(const float4*)(xa + HW), b1 = *(const float4*)(xb + HW), c1 = *(const float4*)(xc + HW);
    float4 a2 = *(const float4*)(xa + 2*(size_t)HW), b2 = *(const float4*)(xb + 2*(size_t)HW), c2 = *(const float4*)(xc + 2*(size_t)HW);
    float4 a3 = *(const float4*)(xa + 3*(size_t)HW), b3 = *(const float4*)(xb + 3*(size_t)HW), c3 = *(const float4*)(xc + 3*(size_t)HW);
    float4 a4 = *(const float4*)(xa + 4*(size_t)HW), b4 = *(const float4*)(xb + 4*(size_t)HW), c4 = *(const float4*)(xc + 4*(size_t)HW);
    float4 pa = *(const float4*)(xa + 5*(size_t)HW), pb = *(const float4*)(xb + 5*(size_t)HW), pc = *(const float4*)(xc + 5*(size_t)HW);
    xa += 6 * (size_t)HW; xb += 6 * (size_t)HW; xc += 6 * (size_t)HW;

    unsigned acc[8];

    #define STEP_FULL(J) { \
        float4 ra = re_full4(a0, a1, a3, a4); \
        float4 rb = re_full4(b0, b1, b3, b4); \
        float4 rc = re_full4(c0, c1, c3, c4); \
        acc[J] = pk_min_f16(acc[J], pk_min_f16(pk_min_f16(mm4(ra), mm4(rb)), mm4(rc))); \
        if constexpr (WGS) *gp = gs4(ra, rb, rc); \
        gp += HW4; \
        a0 = a1; a1 = a2; a2 = a3; a3 = a4; a4 = pa; \
        b0 = b1; b1 = b2; b2 = b3; b3 = b4; b4 = pb; \
        c0 = c1; c1 = c2; c2 = c3; c3 = c4; c4 = pc; }

    #define PREFETCH() { pa = *(const float4*)xa; pb = *(const float4*)xb; pc = *(const float4*)xc; \
                         xa += HW; xb += HW; xc += HW; }

    #define FLUSH(J, T) { unsigned v = acc[J]; \
        v = pk_min_f16(v, (unsigned)__shfl_xor((int)v, 32, 64)); \
        v = pk_min_f16(v, (unsigned)__shfl_xor((int)v, 16, 64)); \
        v = pk_min_f16(v, (unsigned)__shfl_xor((int)v,  8, 64)); \
        v = pk_min_f16(v, (unsigned)__shfl_xor((int)v,  4, 64)); \
        v = pk_min_f16(v, (unsigned)__shfl_xor((int)v,  2, 64)); \
        v = pk_min_f16(v, (unsigned)__shfl_xor((int)v,  1, 64)); \
        if (lane == (T)) keep = v; }

    // tc=0: 4 full groups (t=0..31; prefetch reaches frame 37 <= 63, always valid)
    // tc=1: 3 full groups (t=32..55; prefetch reaches frame 61) + peeled t=56..63
    const int full_groups = 4 - tc;
    for (int g = 0; g < full_groups; ++g) {
        #pragma unroll
        for (int j = 0; j < 8; ++j) acc[j] = 0x7BFF7BFFu;
        #pragma unroll
        for (int j = 0; j < 8; ++j) {
            STEP_FULL(j)
            PREFETCH()
        }
        #pragma unroll
        for (int j = 0; j < 8; ++j) FLUSH(j, g * 8 + j)
    }

    if (tc) {   // peeled final group: t=56..63 (entry: slots=56..60, pa=61, ptr->62)
        #pragma unroll
        for (int j = 0; j < 8; ++j) acc[j] = 0x7BFF7BFFu;
        STEP_FULL(0) PREFETCH()             // t=56, load frame 62
        STEP_FULL(1) PREFETCH()             // t=57, load frame 63
        STEP_FULL(2)                        // t=58
        STEP_FULL(3)                        // t=59 -> a0..a3 = frames 60..63
        {   // t=60: weights -3,-1,1,3
            float4 ra, rb, rc;
            ra.x = fmaf(3.f, a3.x-a0.x, a2.x-a1.x); ra.y = fmaf(3.f, a3.y-a0.y, a2.y-a1.y);
            ra.z = fmaf(3.f, a3.z-a0.z, a2.z-a1.z); ra.w = fmaf(3.f, a3.w-a0.w, a2.w-a1.w);
            rb.x = fmaf(3.f, b3.x-b0.x, b2.x-b1.x); rb.y = fmaf(3.f, b3.y-b0.y, b2.y-b1.y);
            rb.z = fmaf(3.f, b3.z-b0.z, b2.z-b1.z); rb.w = fmaf(3.f, b3.w-b0.w, b2.w-b1.w);
            rc.x = fmaf(3.f, c3.x-c0.x, c2.x-c1.x); rc.y = fmaf(3.f, c3.y-c0.y, c2.y-c1.y);
            rc.z = fmaf(3.f, c3.z-c0.z, c2.z-c1.z); rc.w = fmaf(3.f, c3.w-c0.w, c2.w-c1.w);
            acc[4] = pk_min_f16(acc[4], pk_min_f16(pk_min_f16(mm4(ra), mm4(rb)), mm4(rc)));
            if constexpr (WGS) *gp = gs4(ra, rb, rc);
            gp += HW4;
            a0 = a1; a1 = a2; a2 = a3;
            b0 = b1; b1 = b2; b2 = b3;
            c0 = c1; c1 = c2; c2 = c3;
        }
        {   // t=61: weights -2,0,2
            float4 ra, rb, rc;
            ra.x = 2.f*(a2.x-a0.x); ra.y = 2.f*(a2.y-a0.y); ra.z = 2.f*(a2.z-a0.z); ra.w = 2.f*(a2.w-a0.w);
            rb.x = 2.f*(b2.x-b0.x); rb.y = 2.f*(b2.y-b0.y); rb.z = 2.f*(b2.z-b0.z); rb.w = 2.f*(b2.w-b0.w);
            rc.x = 2.f*(c2.x-c0.x); rc.y = 2.f*(c2.y-c0.y); rc.z = 2.f*(c2.z-c0.z); rc.w = 2.f*(c2.w-c0.w);
            acc[5] = pk_min_f16(acc[5], pk_min_f16(pk_min_f16(mm4(ra), mm4(rb)), mm4(rc)));
            if constexpr (WGS) *gp = gs4(ra, rb, rc);
            gp += HW4;
            a0 = a1; a1 = a2;
            b0 = b1; b1 = b2;
            c0 = c1; c1 = c2;
        }
        {   // t=62: weights -1,1
            float4 ra, rb, rc;
            ra.x = a1.x-a0.x; ra.y = a1.y-a0.y; ra.z = a1.z-a0.z; ra.w = a1.w-a0.w;
            rb.x = b1.x-b0.x; rb.y = b1.y-b0.y; rb.z = b1.z-b0.z; rb.w = b1.w-b0.w;
            rc.x = c1.x-c0.x; rc.y = c1.y-c0.y; rc.z = c1.z-c0.z; rc.w = c1.w-c0.w;
            acc[6] = pk_min_f16(acc[6], pk_min_f16(pk_min_f16(mm4(ra), mm4(rb)), mm4(rc)));
            if constexpr (WGS) *gp = gs4(ra, rb, rc);
            gp += HW4;
        }
        {   // t=63: weight 0 -> re = 0, gs = 0
            acc[7] = pk_min_f16(acc[7], 0u);
            if constexpr (WGS) *gp = make_uint2(0u, 0u);
        }
        #pragma unroll
        for (int j = 0; j < 8; ++j) FLUSH(j, 24 + j)   // local windows 24..31
    }
    #undef STEP_FULL
    #undef PREFETCH
    #undef FLUSH

    if (lane < 32) {   // lane L holds window t0+L: tail gelu eval + LDS reduce
        union { unsigned u; _Float16 h[2]; } cv; cv.u = keep;
        const float amin = (float)cv.h[0];
        const float amax = -(float)cv.h[1];
        const float g0 = gelu_erf(amin), g1 = gelu_erf(amax);
        const float gmax = fmaxf(g0, g1);
        const float XSTAR = -0.7517916f;
        float gmin;
        if (amin >= XSTAR)      gmin = g0;
        else if (amax <= XSTAR) gmin = g1;
        else                    gmin = fminf(gelu_erf(XSTAR), fminf(g0, g1));
        atomicMin(&smin[lane], encf(gmin));
        atomicMax(&smax[lane], encf(gmax));
    }
    __syncthreads();
    const int col = b * 49 + hwb;          // 0..391
    if (tid < 32)            part[(size_t)(t0 + tid) * NBW + col] = smin[tid];
    else if (tid < 64)       part[(size_t)(TT + t0 + tid - 32) * NBW + col] = smax[tid - 32];
}

// block-wide reduce of partial rows tm (min) and 64+tm (max); 256-thread callers
__device__ __forceinline__ void reduce_part(const unsigned* __restrict__ part, int tm,
                                            int tid, float& A, float& Bv) {
    __shared__ unsigned rm[4], rx[4];
    const unsigned* pm = part + (size_t)tm * NBW;
    const unsigned* px = part + (size_t)(TT + tm) * NBW;
    unsigned vmn = 0xFFFFFFFFu, vmx = 0u;
    for (int i = tid; i < NBW; i += 256) {
        vmn = min(vmn, pm[i]);
        vmx = max(vmx, px[i]);
    }
    #pragma unroll
    for (int off = 32; off; off >>= 1) {
        vmn = min(vmn, (unsigned)__shfl_xor((int)vmn, off, 64));
        vmx = max(vmx, (unsigned)__shfl_xor((int)vmx, off, 64));
    }
    if ((tid & 63) == 0) { rm[tid >> 6] = vmn; rx[tid >> 6] = vmx; }
    __syncthreads();
    vmn = min(min(rm[0], rm[1]), min(rm[2], rm[3]));
    vmx = max(max(rx[0], rx[1]), max(rx[2], rx[3]));
    float mn = decf(vmn);
    float mx = decf(vmx) - mn;
    float inv = fast_rcp((mx != 0.f) ? mx : 1e-5f);
    A  = inv;
    Bv = -mn * SUMW * inv;
}

// Pass 3: out[b,t] = (t<4) ? 0 : gs[b,t-4]*A + B; A/B reduced from partials inline.
__global__ __launch_bounds__(256) void k_pass3(const uint2* __restrict__ gs,
                                               const unsigned* __restrict__ part,
                                               float* __restrict__ out) {
    const int bid = blockIdx.x;
    const int b   = bid / 476;             // 476 = 68*7
    const int r   = bid - b * 476;
    const int t   = r / 7;
    const int seg = r - t * 7;
    const int tid = threadIdx.x;
    const int base4 = seg * 1792 + tid;
    float4* op = (float4*)out + ((size_t)b * 68 + t) * HW4 + base4;

    if (t < 4) {
        float4 z = make_float4(0.f, 0.f, 0.f, 0.f);
        #pragma unroll
        for (int k = 0; k < 7; ++k) op[k * 256] = z;
        return;
    }
    const int tm = t - 4;
    float A, Bv;
    reduce_part(part, tm, tid, A, Bv);

    const uint2* gpp = gs + ((size_t)b * TT + tm) * HW4 + base4;
    #pragma unroll
    for (int k = 0; k < 7; ++k) {
        uint2 v = gpp[k * 256];
        union { unsigned u; _Float16 h[2]; } lo, hi; lo.u = v.x; hi.u = v.y;
        float4 o;
        o.x = fmaf((float)lo.h[0], A, Bv);
        o.y = fmaf((float)lo.h[1], A, Bv);
        o.z = fmaf((float)hi.h[0], A, Bv);
        o.w = fmaf((float)hi.h[1], A, Bv);
        op[k * 256] = o;
    }
}

// Fallback helpers (ws too small for gs): consts kernel + direct erf pass
__global__ __launch_bounds__(256) void k_consts(const unsigned* __restrict__ part,
                                                float* __restrict__ ab) {
    const int t = blockIdx.x;              // 64 blocks, one per t
    float A, Bv;
    reduce_part(part, t, threadIdx.x, A, Bv);
    if (threadIdx.x == 0) { ab[t] = A; ab[TT + t] = Bv; }
}

__global__ __launch_bounds__(256) void k_pass2_direct(const float* __restrict__ x,
                                                      const float* __restrict__ ab,
                                                      float* __restrict__ out) {
    __shared__ float sA[TT], sB[TT];
    const int tid = threadIdx.x;
    if (tid < TT)          sA[tid] = ab[tid];
    else if (tid < 2 * TT) sB[tid - TT] = ab[tid];
    __syncthreads();

    const int pix = blockIdx.x * 256 + tid;
    const int b  = pix / HW;
    const int hw = pix - b * HW;
    const float* x0 = x + (size_t)(b * 3) * (TT * (size_t)HW) + hw;
    const float* x1 = x0 + (size_t)TT * HW;
    const float* x2 = x1 + (size_t)TT * HW;
    float* op = out + (size_t)b * (68 * (size_t)HW) + hw;

    op[0] = 0.f; op[HW] = 0.f; op[2 * (size_t)HW] = 0.f; op[3 * (size_t)HW] = 0.f;
    op += 4 * (size_t)HW;

    float a0 = x0[0], a1 = x0[HW], a2 = x0[2*HW], a3 = x0[3*HW], a4 = x0[4*HW];
    float b0 = x1[0], b1 = x1[HW], b2 = x1[2*HW], b3 = x1[3*HW], b4 = x1[4*HW];
    float c0 = x2[0], c1 = x2[HW], c2 = x2[2*HW], c3 = x2[3*HW], c4 = x2[4*HW];

    auto emit = [&](int t, float ra, float rb, float rc) {
        float gsv = 0.2989f * gelu_erf(ra) + 0.587f * gelu_erf(rb) + 0.114f * gelu_erf(rc);
        op[(size_t)t * HW] = fmaf(gsv, sA[t], sB[t]);
    };

    for (int t = 0; t < 59; ++t) {
        emit(t, 4.f*(a4-a0) + 2.f*(a3-a1), 4.f*(b4-b0) + 2.f*(b3-b1), 4.f*(c4-c0) + 2.f*(c3-c1));
        a0=a1; a1=a2; a2=a3; a3=a4; a4 = x0[(size_t)(t+5)*HW];
        b0=b1; b1=b2; b2=b3; b3=b4; b4 = x1[(size_t)(t+5)*HW];
        c0=c1; c1=c2; c2=c3; c3=c4; c4 = x2[(size_t)(t+5)*HW];
    }
    emit(59, 4.f*(a4-a0) + 2.f*(a3-a1), 4.f*(b4-b0) + 2.f*(b3-b1), 4.f*(c4-c0) + 2.f*(c3-c1));
    a0=a1; a1=a2; a2=a3; a3=a4; b0=b1; b1=b2; b2=b3; b3=b4; c0=c1; c1=c2; c2=c3; c3=c4;
    emit(60, 3.f*(a3-a0) + (a2-a1), 3.f*(b3-b0) + (b2-b1), 3.f*(c3-c0) + (c2-c1));
    a0=a1; a1=a2; a2=a3; b0=b1; b1=b2; b2=b3; c0=c1; c1=c2; c2=c3;
    emit(61, 2.f*(a2-a0), 2.f*(b2-b0), 2.f*(c2-c0));
    a0=a1; a1=a2; b0=b1; b1=b2; c0=c1; c1=c2;
    emit(62, a1-a0, b1-b0, c1-c0);
    op[63 * (size_t)HW] = sB[63];
}

extern "C" void kernel_launch(void* const* d_in, const int* in_sizes, int n_in,
                              void* d_out, int out_size, void* d_ws, size_t ws_size,
                              hipStream_t stream) {
    const float* x = (const float*)d_in[0];
    float* out = (float*)d_out;
    // ws layout: [0,1024): ab (fallback); [1024, +200704): part (128 rows × 392);
    //            then gs (~51.4MB)
    float* ab = (float*)d_ws;
    unsigned* part = (unsigned*)((char*)d_ws + 1024);
    const size_t part_bytes = (size_t)2 * TT * NBW * 4;           // 200704
    uint2* gs = (uint2*)((char*)d_ws + 1024 + part_bytes);
    const size_t need = 1024 + part_bytes + (size_t)8 * TT * (size_t)HW4 * 8;  // ~51.6 MB

    if (ws_size >= need) {
        k_pass1<true><<<2 * NBW, 256, 0, stream>>>(x, part, gs);
        k_pass3<<<3808, 256, 0, stream>>>(gs, part, out);
    } else if (ws_size >= 1024 + part_bytes) {
        k_pass1<false><<<2 * NBW, 256, 0, stream>>>(x, part, nullptr);
        k_consts<<<TT, 256, 0, stream>>>(part, ab);
        k_pass2_direct<<<1568, 256, 0, stream>>>(x, ab, out);
    }
}

// Round 15
// 124.999 us; speedup vs baseline: 1.0264x; 1.0264x over previous
//
#include <hip/hip_runtime.h>

#define HW 50176            // 224*224
#define HW2 25088           // HW/2
#define HW4 12544           // HW/4
#define TT 64
#define NBLK 784            // fused grid: 8 b × 98 hwb, 256 thr, 2 px/thread (all co-resident at 4 blk/CU)
#define NBP 784             // fallback partial width
#define SUMW 0.9999f        // 0.2989+0.587+0.114
#define XSTAR -0.7517916f   // argmin of gelu

__device__ __forceinline__ float gelu_erf(float x) {
    return 0.5f * x * (1.0f + erff(0.70710678f * x));
}
__device__ __forceinline__ float fast_rcp(float v) {
    float r; asm("v_rcp_f32 %0, %1" : "=v"(r) : "v"(v)); return r;
}
__device__ __forceinline__ float gelu_fast(float x) {
    // tanh-form gelu; max |err| ~3e-3 vs erf (cancels through normalize)
    float x2 = x * x;
    float e = exp2f(-x * fmaf(0.1029433f, x2, 2.3022078f));
    return x * fast_rcp(1.0f + e);
}
__device__ __forceinline__ unsigned encf(float f) {
    unsigned u = __float_as_uint(f);
    return (u & 0x80000000u) ? ~u : (u | 0x80000000u);
}
__device__ __forceinline__ float decf(unsigned u) {
    unsigned b = (u & 0x80000000u) ? (u ^ 0x80000000u) : ~u;
    return __uint_as_float(b);
}
__device__ __forceinline__ unsigned pk_min_f16(unsigned a, unsigned b) {
    unsigned r; asm("v_pk_min_f16 %0, %1, %2" : "=v"(r) : "v"(a), "v"(b)); return r;
}
__device__ __forceinline__ unsigned pack2(float lo, float hi) {
    auto p = __builtin_amdgcn_cvt_pkrtz(lo, hi);
    return __builtin_bit_cast(unsigned, p);
}
__device__ __forceinline__ unsigned pk2(float r) { return pack2(r, -r); }
__device__ __forceinline__ unsigned mm2(float2 r) { return pk_min_f16(pk2(r.x), pk2(r.y)); }
__device__ __forceinline__ float2 re_full2(float2 w0, float2 w1, float2 w3, float2 w4) {
    float2 r;
    r.x = fmaf(4.f, w4.x - w0.x, 2.f * (w3.x - w1.x));
    r.y = fmaf(4.f, w4.y - w0.y, 2.f * (w3.y - w1.y));
    return r;
}
// u8 quantize: q = gs*qs + 8.5 (offset 8 = zero point, step 1/qs), clamped
__device__ __forceinline__ unsigned q8(float g, float qs) {
    return (unsigned)fmaxf(0.f, fminf(255.f, fmaf(g, qs, 8.5f)));
}

// ===================== FUSED single-kernel path (grid barrier) =====================
// Phase A: per-thread 2px sliding window over all 64 frames x 3ch; track f16 (min re,
// min -re) per t -> global atomicMin on gmm; keep gs as u8x2-per-window in gsr[32].
// Grid barrier (counter spin; all 784 blocks co-resident by launch guard).
// Phase C: 64 threads derive A/B per t from gmm (erf + unimodal bracket), all threads
// decode gsr and write out (+4 zero frames).
__global__ __launch_bounds__(256, 4) void k_fused(const float* __restrict__ x,
                                                  unsigned* __restrict__ gmm,
                                                  unsigned* __restrict__ cnt,
                                                  float* __restrict__ out) {
    __shared__ unsigned smin[TT], smax[TT];   // both min-encoded (smax tracks min(-re))
    __shared__ float sA[TT], sB[TT];
    const int tid = threadIdx.x;
    if (tid < TT) smin[tid] = 0xFFFFFFFFu;
    else if (tid < 2 * TT) smax[tid - TT] = 0xFFFFFFFFu;
    __syncthreads();

    const int bid = blockIdx.x;            // < 784 = 8 b × 98 hwb
    const int b   = bid / 98;
    const int hwb = bid - b * 98;
    const int hw  = (hwb * 256 + tid) * 2;
    const float* xa = x + ((size_t)(b * 3 + 0) * TT) * (size_t)HW + hw;
    const float* xb = x + ((size_t)(b * 3 + 1) * TT) * (size_t)HW + hw;
    const float* xc = x + ((size_t)(b * 3 + 2) * TT) * (size_t)HW + hw;

    const int lane = tid & 63;
    unsigned keep = 0x7BFF7BFFu;

    float2 a0 = *(const float2*)xa, b0 = *(const float2*)xb, c0 = *(const float2*)xc;
    float2 a1 = *(const float2*)(xa + HW), b1 = *(const float2*)(xb + HW), c1 = *(const float2*)(xc + HW);
    float2 a2 = *(const float2*)(xa + 2*(size_t)HW), b2 = *(const float2*)(xb + 2*(size_t)HW), c2 = *(const float2*)(xc + 2*(size_t)HW);
    float2 a3 = *(const float2*)(xa + 3*(size_t)HW), b3 = *(const float2*)(xb + 3*(size_t)HW), c3 = *(const float2*)(xc + 3*(size_t)HW);
    float2 a4 = *(const float2*)(xa + 4*(size_t)HW), b4 = *(const float2*)(xb + 4*(size_t)HW), c4 = *(const float2*)(xc + 4*(size_t)HW);
    float2 pa = *(const float2*)(xa + 5*(size_t)HW), pb = *(const float2*)(xb + 5*(size_t)HW), pc = *(const float2*)(xc + 5*(size_t)HW);
    xa += 6 * (size_t)HW; xb += 6 * (size_t)HW; xc += 6 * (size_t)HW;

    unsigned acc[8];
    unsigned gsr[32];                      // u8 gs payload: [w>>1] = bx0|by0<<8|bx1<<16|by1<<24
    unsigned hp = 0;

    #define STEP(G,J) { \
        const int w = (G)*8 + (J); \
        const float qs = (w < 60) ? 8.f : (w == 60 ? 11.313708f : (w == 61 ? 17.888544f : (w == 62 ? 35.777088f : 8.f))); \
        float2 ra, rb, rc; \
        if (w < 60) { \
            ra = re_full2(a0, a1, a3, a4); rb = re_full2(b0, b1, b3, b4); rc = re_full2(c0, c1, c3, c4); \
        } else if (w == 60) { \
            ra.x = fmaf(3.f, a3.x - a0.x, a2.x - a1.x); ra.y = fmaf(3.f, a3.y - a0.y, a2.y - a1.y); \
            rb.x = fmaf(3.f, b3.x - b0.x, b2.x - b1.x); rb.y = fmaf(3.f, b3.y - b0.y, b2.y - b1.y); \
            rc.x = fmaf(3.f, c3.x - c0.x, c2.x - c1.x); rc.y = fmaf(3.f, c3.y - c0.y, c2.y - c1.y); \
        } else if (w == 61) { \
            ra.x = 2.f*(a2.x - a0.x); ra.y = 2.f*(a2.y - a0.y); \
            rb.x = 2.f*(b2.x - b0.x); rb.y = 2.f*(b2.y - b0.y); \
            rc.x = 2.f*(c2.x - c0.x); rc.y = 2.f*(c2.y - c0.y); \
        } else if (w == 62) { \
            ra.x = a1.x - a0.x; ra.y = a1.y - a0.y; \
            rb.x = b1.x - b0.x; rb.y = b1.y - b0.y; \
            rc.x = c1.x - c0.x; rc.y = c1.y - c0.y; \
        } else { \
            ra.x = 0.f; ra.y = 0.f; rb = ra; rc = ra; \
        } \
        acc[J] = pk_min_f16(acc[J], pk_min_f16(pk_min_f16(mm2(ra), mm2(rb)), mm2(rc))); \
        float gx = fmaf(0.114f, gelu_fast(rc.x), fmaf(0.587f, gelu_fast(rb.x), 0.2989f * gelu_fast(ra.x))); \
        float gy = fmaf(0.114f, gelu_fast(rc.y), fmaf(0.587f, gelu_fast(rb.y), 0.2989f * gelu_fast(ra.y))); \
        unsigned bx = q8(gx, qs), by = q8(gy, qs); \
        if ((w & 1) == 0) hp = bx | (by << 8); \
        else              gsr[w >> 1] = hp | (bx << 16) | (by << 24); \
        a0 = a1; a1 = a2; a2 = a3; a3 = a4; a4 = pa; \
        b0 = b1; b1 = b2; b2 = b3; b3 = b4; b4 = pb; \
        c0 = c1; c1 = c2; c2 = c3; c3 = c4; c4 = pc; \
        if (w <= 57) { pa = *(const float2*)xa; pb = *(const float2*)xb; pc = *(const float2*)xc; \
                       xa += HW; xb += HW; xc += HW; } \
    }

    #define FLUSH(J, T) { unsigned v = acc[J]; \
        v = pk_min_f16(v, (unsigned)__shfl_xor((int)v, 32, 64)); \
        v = pk_min_f16(v, (unsigned)__shfl_xor((int)v, 16, 64)); \
        v = pk_min_f16(v, (unsigned)__shfl_xor((int)v,  8, 64)); \
        v = pk_min_f16(v, (unsigned)__shfl_xor((int)v,  4, 64)); \
        v = pk_min_f16(v, (unsigned)__shfl_xor((int)v,  2, 64)); \
        v = pk_min_f16(v, (unsigned)__shfl_xor((int)v,  1, 64)); \
        if (lane == (T)) keep = v; }

    #pragma unroll
    for (int g = 0; g < 8; ++g) {
        #pragma unroll
        for (int j = 0; j < 8; ++j) acc[j] = 0x7BFF7BFFu;
        #pragma unroll
        for (int j = 0; j < 8; ++j) STEP(g, j)
        #pragma unroll
        for (int j = 0; j < 8; ++j) FLUSH(j, g * 8 + j)
    }
    #undef STEP
    #undef FLUSH

    {   // lane L holds f16 (min re, min -re) for window t=L (its wave's reduction)
        union { unsigned u; _Float16 h[2]; } cv; cv.u = keep;
        atomicMin(&smin[lane], encf((float)cv.h[0]));   // min re
        atomicMin(&smax[lane], encf((float)cv.h[1]));   // min(-re) == -(max re)
    }
    __syncthreads();
    if (tid < TT)            atomicMin(&gmm[tid], smin[tid]);
    else if (tid < 2 * TT)   atomicMin(&gmm[tid], smax[tid - TT]);

    // ---- grid barrier (all NBLK blocks co-resident; guarded at launch) ----
    __syncthreads();                        // drains vmcnt -> this block's atomics complete
    if (tid == 0) {
        __hip_atomic_fetch_add(cnt, 1u, __ATOMIC_RELEASE, __HIP_MEMORY_SCOPE_AGENT);
        while (__hip_atomic_load(cnt, __ATOMIC_ACQUIRE, __HIP_MEMORY_SCOPE_AGENT) < NBLK)
            __builtin_amdgcn_s_sleep(2);
    }
    __syncthreads();

    // ---- Phase C ----
    if (tid < TT) {
        float rmin =  decf(__hip_atomic_load(&gmm[tid],      __ATOMIC_RELAXED, __HIP_MEMORY_SCOPE_AGENT));
        float rmax = -decf(__hip_atomic_load(&gmm[TT + tid], __ATOMIC_RELAXED, __HIP_MEMORY_SCOPE_AGENT));
        float g0 = gelu_erf(rmin), g1 = gelu_erf(rmax);
        float gmaxv = fmaxf(g0, g1);
        float gminv;
        if (rmin >= XSTAR)      gminv = g0;
        else if (rmax <= XSTAR) gminv = g1;
        else                    gminv = fminf(gelu_erf(XSTAR), fminf(g0, g1));
        float mx = gmaxv - gminv;
        float inv = fast_rcp((mx != 0.f) ? mx : 1e-5f);
        sA[tid] = inv;
        sB[tid] = -gminv * SUMW * inv;
    }
    __syncthreads();

    float* op = out + (size_t)b * (68 * (size_t)HW) + hw;
    const float2 z2 = make_float2(0.f, 0.f);
    *(float2*)op = z2;
    *(float2*)(op + HW) = z2;
    *(float2*)(op + 2 * (size_t)HW) = z2;
    *(float2*)(op + 3 * (size_t)HW) = z2;
    op += 4 * (size_t)HW;
    #pragma unroll
    for (int i = 0; i < 32; ++i) {
        const int t0 = 2 * i, t1 = 2 * i + 1;
        const float iq0 = (t0 < 60) ? 0.125f : (t0 == 60 ? 0.08838835f : 0.02795085f);   // t0 ∈ {even} -> 60 or 62
        const float iq1 = (t1 < 60) ? 0.125f : (t1 == 61 ? 0.05590170f : 0.125f);        // t1 odd -> 61 or 63
        unsigned v = gsr[i];
        float A0 = sA[t0], B0 = sB[t0], A1 = sA[t1], B1 = sB[t1];
        float2 o0, o1;
        o0.x = fmaf(((float)(int)( v        & 255u) - 8.f) * iq0, A0, B0);
        o0.y = fmaf(((float)(int)((v >>  8) & 255u) - 8.f) * iq0, A0, B0);
        o1.x = fmaf(((float)(int)((v >> 16) & 255u) - 8.f) * iq1, A1, B1);
        o1.y = fmaf(((float)(int)( v >> 24        ) - 8.f) * iq1, A1, B1);
        *(float2*)(op + (size_t)t0 * HW) = o0;
        *(float2*)(op + (size_t)t1 * HW) = o1;
    }
}

// ===================== FALLBACK: round-11 two/three-kernel path =====================
template<bool WGS>
__global__ __launch_bounds__(256, 4) void k_pass1(const float* __restrict__ x,
                                                  unsigned* __restrict__ part,
                                                  unsigned* __restrict__ gs) {
    __shared__ unsigned smin[TT], smax[TT];
    const int tid = threadIdx.x;
    if (tid < TT) smin[tid] = 0xFFFFFFFFu;
    else if (tid < 2 * TT) smax[tid - TT] = 0u;
    __syncthreads();

    const int bid = blockIdx.x;
    const int b   = bid / 98;
    const int hwb = bid - b * 98;
    const int hw  = (hwb * 256 + tid) * 2;
    const float* xa = x + ((size_t)(b * 3 + 0) * TT) * (size_t)HW + hw;
    const float* xb = x + ((size_t)(b * 3 + 1) * TT) * (size_t)HW + hw;
    const float* xc = x + ((size_t)(b * 3 + 2) * TT) * (size_t)HW + hw;
    unsigned* gp = gs + ((size_t)b * TT) * (size_t)HW2 + (hwb * 256 + tid);

    const int lane = tid & 63;
    unsigned keep = 0x7BFF7BFFu;

    float2 a0 = *(const float2*)xa, b0 = *(const float2*)xb, c0 = *(const float2*)xc;
    float2 a1 = *(const float2*)(xa + HW), b1 = *(const float2*)(xb + HW), c1 = *(const float2*)(xc + HW);
    float2 a2 = *(const float2*)(xa + 2*(size_t)HW), b2 = *(const float2*)(xb + 2*(size_t)HW), c2 = *(const float2*)(xc + 2*(size_t)HW);
    float2 a3 = *(const float2*)(xa + 3*(size_t)HW), b3 = *(const float2*)(xb + 3*(size_t)HW), c3 = *(const float2*)(xc + 3*(size_t)HW);
    float2 a4 = *(const float2*)(xa + 4*(size_t)HW), b4 = *(const float2*)(xb + 4*(size_t)HW), c4 = *(const float2*)(xc + 4*(size_t)HW);
    float2 pa = *(const float2*)(xa + 5*(size_t)HW), pb = *(const float2*)(xb + 5*(size_t)HW), pc = *(const float2*)(xc + 5*(size_t)HW);
    xa += 6 * (size_t)HW; xb += 6 * (size_t)HW; xc += 6 * (size_t)HW;

    unsigned acc[8];

    #define STEP_FULL(J) { \
        float2 ra = re_full2(a0, a1, a3, a4); \
        float2 rb = re_full2(b0, b1, b3, b4); \
        float2 rc = re_full2(c0, c1, c3, c4); \
        acc[J] = pk_min_f16(acc[J], pk_min_f16(pk_min_f16(mm2(ra), mm2(rb)), mm2(rc))); \
        if constexpr (WGS) { \
            float gx = fmaf(0.114f, gelu_fast(rc.x), fmaf(0.587f, gelu_fast(rb.x), 0.2989f * gelu_fast(ra.x))); \
            float gy = fmaf(0.114f, gelu_fast(rc.y), fmaf(0.587f, gelu_fast(rb.y), 0.2989f * gelu_fast(ra.y))); \
            *gp = pack2(gx, gy); \
        } \
        gp += HW2; \
        a0 = a1; a1 = a2; a2 = a3; a3 = a4; a4 = pa; \
        b0 = b1; b1 = b2; b2 = b3; b3 = b4; b4 = pb; \
        c0 = c1; c1 = c2; c2 = c3; c3 = c4; c4 = pc; }

    #define PREFETCH() { pa = *(const float2*)xa; pb = *(const float2*)xb; pc = *(const float2*)xc; \
                         xa += HW; xb += HW; xc += HW; }

    #define FLUSH(J, T) { unsigned v = acc[J]; \
        v = pk_min_f16(v, (unsigned)__shfl_xor((int)v, 32, 64)); \
        v = pk_min_f16(v, (unsigned)__shfl_xor((int)v, 16, 64)); \
        v = pk_min_f16(v, (unsigned)__shfl_xor((int)v,  8, 64)); \
        v = pk_min_f16(v, (unsigned)__shfl_xor((int)v,  4, 64)); \
        v = pk_min_f16(v, (unsigned)__shfl_xor((int)v,  2, 64)); \
        v = pk_min_f16(v, (unsigned)__shfl_xor((int)v,  1, 64)); \
        if (lane == (T)) keep = v; }

    for (int g = 0; g < 7; ++g) {
        #pragma unroll
        for (int j = 0; j < 8; ++j) acc[j] = 0x7BFF7BFFu;
        #pragma unroll
        for (int j = 0; j < 8; ++j) { STEP_FULL(j) PREFETCH() }
        #pragma unroll
        for (int j = 0; j < 8; ++j) FLUSH(j, g * 8 + j)
    }
    {
        #pragma unroll
        for (int j = 0; j < 8; ++j) acc[j] = 0x7BFF7BFFu;
        STEP_FULL(0) PREFETCH()
        STEP_FULL(1) PREFETCH()
        STEP_FULL(2)
        STEP_FULL(3)
        {
            float2 ra, rb, rc;
            ra.x = fmaf(3.f, a3.x - a0.x, a2.x - a1.x); ra.y = fmaf(3.f, a3.y - a0.y, a2.y - a1.y);
            rb.x = fmaf(3.f, b3.x - b0.x, b2.x - b1.x); rb.y = fmaf(3.f, b3.y - b0.y, b2.y - b1.y);
            rc.x = fmaf(3.f, c3.x - c0.x, c2.x - c1.x); rc.y = fmaf(3.f, c3.y - c0.y, c2.y - c1.y);
            acc[4] = pk_min_f16(acc[4], pk_min_f16(pk_min_f16(mm2(ra), mm2(rb)), mm2(rc)));
            if constexpr (WGS) {
                float gx = fmaf(0.114f, gelu_fast(rc.x), fmaf(0.587f, gelu_fast(rb.x), 0.2989f * gelu_fast(ra.x)));
                float gy = fmaf(0.114f, gelu_fast(rc.y), fmaf(0.587f, gelu_fast(rb.y), 0.2989f * gelu_fast(ra.y)));
                *gp = pack2(gx, gy);
            }
            gp += HW2;
            a0 = a1; a1 = a2; a2 = a3;
            b0 = b1; b1 = b2; b2 = b3;
            c0 = c1; c1 = c2; c2 = c3;
        }
        {
            float2 ra, rb, rc;
            ra.x = 2.f*(a2.x-a0.x); ra.y = 2.f*(a2.y-a0.y);
            rb.x = 2.f*(b2.x-b0.x); rb.y = 2.f*(b2.y-b0.y);
            rc.x = 2.f*(c2.x-c0.x); rc.y = 2.f*(c2.y-c0.y);
            acc[5] = pk_min_f16(acc[5], pk_min_f16(pk_min_f16(mm2(ra), mm2(rb)), mm2(rc)));
            if constexpr (WGS) {
                float gx = fmaf(0.114f, gelu_fast(rc.x), fmaf(0.587f, gelu_fast(rb.x), 0.2989f * gelu_fast(ra.x)));
                float gy = fmaf(0.114f, gelu_fast(rc.y), fmaf(0.587f, gelu_fast(rb.y), 0.2989f * gelu_fast(ra.y)));
                *gp = pack2(gx, gy);
            }
            gp += HW2;
            a0 = a1; a1 = a2;
            b0 = b1; b1 = b2;
            c0 = c1; c1 = c2;
        }
        {
            float2 ra, rb, rc;
            ra.x = a1.x-a0.x; ra.y = a1.y-a0.y;
            rb.x = b1.x-b0.x; rb.y = b1.y-b0.y;
            rc.x = c1.x-c0.x; rc.y = c1.y-c0.y;
            acc[6] = pk_min_f16(acc[6], pk_min_f16(pk_min_f16(mm2(ra), mm2(rb)), mm2(rc)));
            if constexpr (WGS) {
                float gx = fmaf(0.114f, gelu_fast(rc.x), fmaf(0.587f, gelu_fast(rb.x), 0.2989f * gelu_fast(ra.x)));
                float gy = fmaf(0.114f, gelu_fast(rc.y), fmaf(0.587f, gelu_fast(rb.y), 0.2989f * gelu_fast(ra.y)));
                *gp = pack2(gx, gy);
            }
            gp += HW2;
        }
        {
            acc[7] = pk_min_f16(acc[7], 0u);
            if constexpr (WGS) *gp = 0u;
        }
        #pragma unroll
        for (int j = 0; j < 8; ++j) FLUSH(j, 56 + j)
    }
    #undef STEP_FULL
    #undef PREFETCH
    #undef FLUSH

    {
        union { unsigned u; _Float16 h[2]; } cv; cv.u = keep;
        const float amin = (float)cv.h[0];
        const float amax = -(float)cv.h[1];
        const float g0 = gelu_erf(amin), g1 = gelu_erf(amax);
        const float gmax = fmaxf(g0, g1);
        float gmin;
        if (amin >= XSTAR)      gmin = g0;
        else if (amax <= XSTAR) gmin = g1;
        else                    gmin = fminf(gelu_erf(XSTAR), fminf(g0, g1));
        atomicMin(&smin[lane], encf(gmin));
        atomicMax(&smax[lane], encf(gmax));
    }
    __syncthreads();
    if (tid < TT)            part[(size_t)tid * NBP + bid] = smin[tid];
    else if (tid < 2 * TT)   part[(size_t)tid * NBP + bid] = smax[tid - TT];
}

__device__ __forceinline__ void reduce_part(const unsigned* __restrict__ part, int tm,
                                            int tid, float& A, float& Bv) {
    __shared__ unsigned rm[4], rx[4];
    const unsigned* pm = part + (size_t)tm * NBP;
    const unsigned* px = part + (size_t)(TT + tm) * NBP;
    unsigned vmn = 0xFFFFFFFFu, vmx = 0u;
    for (int i = tid; i < NBP; i += 256) {
        vmn = min(vmn, pm[i]);
        vmx = max(vmx, px[i]);
    }
    #pragma unroll
    for (int off = 32; off; off >>= 1) {
        vmn = min(vmn, (unsigned)__shfl_xor((int)vmn, off, 64));
        vmx = max(vmx, (unsigned)__shfl_xor((int)vmx, off, 64));
    }
    if ((tid & 63) == 0) { rm[tid >> 6] = vmn; rx[tid >> 6] = vmx; }
    __syncthreads();
    vmn = min(min(rm[0], rm[1]), min(rm[2], rm[3]));
    vmx = max(max(rx[0], rx[1]), max(rx[2], rx[3]));
    float mn = decf(vmn);
    float mx = decf(vmx) - mn;
    float inv = fast_rcp((mx != 0.f) ? mx : 1e-5f);
    A  = inv;
    Bv = -mn * SUMW * inv;
}

__global__ __launch_bounds__(256) void k_pass3(const unsigned* __restrict__ gs,
                                               const unsigned* __restrict__ part,
                                               float* __restrict__ out) {
    const int bid = blockIdx.x;
    const int b   = bid / 476;
    const int r   = bid - b * 476;
    const int t   = r / 7;
    const int seg = r - t * 7;
    const int tid = threadIdx.x;
    const int base4 = seg * 1792 + tid;
    float4* op = (float4*)out + ((size_t)b * 68 + t) * HW4 + base4;

    if (t < 4) {
        float4 z = make_float4(0.f, 0.f, 0.f, 0.f);
        #pragma unroll
        for (int k = 0; k < 7; ++k) op[k * 256] = z;
        return;
    }
    const int tm = t - 4;
    float A, Bv;
    reduce_part(part, tm, tid, A, Bv);

    const uint2* gpp = (const uint2*)gs + ((size_t)b * TT + tm) * HW4 + base4;
    #pragma unroll
    for (int k = 0; k < 7; ++k) {
        uint2 v = gpp[k * 256];
        union { unsigned u; _Float16 h[2]; } lo, hi; lo.u = v.x; hi.u = v.y;
        float4 o;
        o.x = fmaf((float)lo.h[0], A, Bv);
        o.y = fmaf((float)lo.h[1], A, Bv);
        o.z = fmaf((float)hi.h[0], A, Bv);
        o.w = fmaf((float)hi.h[1], A, Bv);
        op[k * 256] = o;
    }
}

extern "C" void kernel_launch(void* const* d_in, const int* in_sizes, int n_in,
                              void* d_out, int out_size, void* d_ws, size_t ws_size,
                              hipStream_t stream) {
    const float* x = (const float*)d_in[0];
    float* out = (float*)d_out;
    // ws: [0,512): gmm (128 u32, min-encoded both rows); [512,516): cnt;
    //     [4096, +401408): part (fallback); then gs (fallback, ~51.4MB)
    unsigned* gmm = (unsigned*)d_ws;
    unsigned* cnt = (unsigned*)((char*)d_ws + 512);
    unsigned* part = (unsigned*)((char*)d_ws + 4096);
    const size_t part_bytes = (size_t)2 * TT * NBP * 4;
    unsigned* gs = (unsigned*)((char*)d_ws + 4096 + part_bytes);
    const size_t need_fb = 4096 + part_bytes + (size_t)8 * TT * (size_t)HW2 * 4;

    int dev = 0;
    (void)hipGetDevice(&dev);
    int ncu = 0;
    (void)hipDeviceGetAttribute(&ncu, hipDeviceAttributeMultiprocessorCount, dev);
    int maxb = 0;
    (void)hipOccupancyMaxActiveBlocksPerMultiprocessor(&maxb, k_fused, 256, 0);

    if ((long long)maxb * (long long)ncu >= NBLK) {
        hipMemsetAsync(gmm, 0xFF, 2 * TT * sizeof(unsigned), stream);
        hipMemsetAsync(cnt, 0, sizeof(unsigned), stream);
        k_fused<<<NBLK, 256, 0, stream>>>(x, gmm, cnt, out);
    } else if (ws_size >= need_fb) {
        k_pass1<true><<<NBP, 256, 0, stream>>>(x, part, gs);
        k_pass3<<<3808, 256, 0, stream>>>(gs, part, out);
    }
}

// Round 16
// 124.208 us; speedup vs baseline: 1.0330x; 1.0064x over previous
//
#include <hip/hip_runtime.h>

#define HW 50176            // 224*224
#define HW2 25088           // HW/2
#define HW4 12544           // HW/4
#define TT 64
#define NBLK 784            // fused grid: 8 b × 98 hwb, 256 thr, 2 px/thread (all co-resident at 4 blk/CU)
#define NBP 784             // fallback partial width
#define SUMW 0.9999f        // 0.2989+0.587+0.114
#define XSTAR -0.7517916f   // argmin of gelu

__device__ __forceinline__ float gelu_erf(float x) {
    return 0.5f * x * (1.0f + erff(0.70710678f * x));
}
__device__ __forceinline__ float fast_rcp(float v) {
    float r; asm("v_rcp_f32 %0, %1" : "=v"(r) : "v"(v)); return r;
}
__device__ __forceinline__ float gelu_fast(float x) {
    // tanh-form gelu; max |err| ~3e-3 vs erf (cancels through normalize)
    float x2 = x * x;
    float e = exp2f(-x * fmaf(0.1029433f, x2, 2.3022078f));
    return x * fast_rcp(1.0f + e);
}
__device__ __forceinline__ unsigned encf(float f) {
    unsigned u = __float_as_uint(f);
    return (u & 0x80000000u) ? ~u : (u | 0x80000000u);
}
__device__ __forceinline__ float decf(unsigned u) {
    unsigned b = (u & 0x80000000u) ? (u ^ 0x80000000u) : ~u;
    return __uint_as_float(b);
}
__device__ __forceinline__ unsigned pk_min_f16(unsigned a, unsigned b) {
    unsigned r; asm("v_pk_min_f16 %0, %1, %2" : "=v"(r) : "v"(a), "v"(b)); return r;
}
__device__ __forceinline__ unsigned pack2(float lo, float hi) {
    auto p = __builtin_amdgcn_cvt_pkrtz(lo, hi);
    return __builtin_bit_cast(unsigned, p);
}
__device__ __forceinline__ unsigned pk2(float r) { return pack2(r, -r); }
__device__ __forceinline__ unsigned mm2(float2 r) { return pk_min_f16(pk2(r.x), pk2(r.y)); }
__device__ __forceinline__ float2 re_full2(float2 w0, float2 w1, float2 w3, float2 w4) {
    float2 r;
    r.x = fmaf(4.f, w4.x - w0.x, 2.f * (w3.x - w1.x));
    r.y = fmaf(4.f, w4.y - w0.y, 2.f * (w3.y - w1.y));
    return r;
}
// u8 quantize: q = gs*qs + 8.5 (offset 8 = zero point, step 1/qs), clamped
__device__ __forceinline__ unsigned q8(float g, float qs) {
    return (unsigned)fmaxf(0.f, fminf(255.f, fmaf(g, qs, 8.5f)));
}

// ===================== FUSED single-kernel path (grid barrier) =====================
// Phase A: per-thread 2px sliding window over all 64 frames x 3ch; track f16 (min re,
// min -re) per t -> global atomicMin on gmm; keep gs as u8x2-per-window in gsr[32].
// Grid barrier (counter spin; all 784 blocks co-resident by launch guard).
// Phase C: 64 threads derive A/B per t from gmm (erf + unimodal bracket), all threads
// decode gsr and write out (+4 zero frames).
__global__ __launch_bounds__(256, 4) void k_fused(const float* __restrict__ x,
                                                  unsigned* __restrict__ gmm,
                                                  unsigned* __restrict__ cnt,
                                                  float* __restrict__ out) {
    __shared__ unsigned smin[TT], smax[TT];   // both min-encoded (smax tracks min(-re))
    __shared__ float sA[TT], sB[TT];
    const int tid = threadIdx.x;
    if (tid < TT) smin[tid] = 0xFFFFFFFFu;
    else if (tid < 2 * TT) smax[tid - TT] = 0xFFFFFFFFu;
    __syncthreads();

    const int bid = blockIdx.x;            // < 784 = 8 b × 98 hwb
    const int b   = bid / 98;
    const int hwb = bid - b * 98;
    const int hw  = (hwb * 256 + tid) * 2;
    const float* xa = x + ((size_t)(b * 3 + 0) * TT) * (size_t)HW + hw;
    const float* xb = x + ((size_t)(b * 3 + 1) * TT) * (size_t)HW + hw;
    const float* xc = x + ((size_t)(b * 3 + 2) * TT) * (size_t)HW + hw;

    const int lane = tid & 63;
    unsigned keep = 0x7BFF7BFFu;

    float2 a0 = *(const float2*)xa, b0 = *(const float2*)xb, c0 = *(const float2*)xc;
    float2 a1 = *(const float2*)(xa + HW), b1 = *(const float2*)(xb + HW), c1 = *(const float2*)(xc + HW);
    float2 a2 = *(const float2*)(xa + 2*(size_t)HW), b2 = *(const float2*)(xb + 2*(size_t)HW), c2 = *(const float2*)(xc + 2*(size_t)HW);
    float2 a3 = *(const float2*)(xa + 3*(size_t)HW), b3 = *(const float2*)(xb + 3*(size_t)HW), c3 = *(const float2*)(xc + 3*(size_t)HW);
    float2 a4 = *(const float2*)(xa + 4*(size_t)HW), b4 = *(const float2*)(xb + 4*(size_t)HW), c4 = *(const float2*)(xc + 4*(size_t)HW);
    float2 pa = *(const float2*)(xa + 5*(size_t)HW), pb = *(const float2*)(xb + 5*(size_t)HW), pc = *(const float2*)(xc + 5*(size_t)HW);
    xa += 6 * (size_t)HW; xb += 6 * (size_t)HW; xc += 6 * (size_t)HW;

    unsigned acc[8];
    unsigned gsr[32];                      // u8 gs payload: [w>>1] = bx0|by0<<8|bx1<<16|by1<<24
    unsigned hp = 0;

    #define STEP(G,J) { \
        const int w = (G)*8 + (J); \
        const float qs = (w < 60) ? 8.f : (w == 60 ? 11.313708f : (w == 61 ? 17.888544f : (w == 62 ? 35.777088f : 8.f))); \
        float2 ra, rb, rc; \
        if (w < 60) { \
            ra = re_full2(a0, a1, a3, a4); rb = re_full2(b0, b1, b3, b4); rc = re_full2(c0, c1, c3, c4); \
        } else if (w == 60) { \
            ra.x = fmaf(3.f, a3.x - a0.x, a2.x - a1.x); ra.y = fmaf(3.f, a3.y - a0.y, a2.y - a1.y); \
            rb.x = fmaf(3.f, b3.x - b0.x, b2.x - b1.x); rb.y = fmaf(3.f, b3.y - b0.y, b2.y - b1.y); \
            rc.x = fmaf(3.f, c3.x - c0.x, c2.x - c1.x); rc.y = fmaf(3.f, c3.y - c0.y, c2.y - c1.y); \
        } else if (w == 61) { \
            ra.x = 2.f*(a2.x - a0.x); ra.y = 2.f*(a2.y - a0.y); \
            rb.x = 2.f*(b2.x - b0.x); rb.y = 2.f*(b2.y - b0.y); \
            rc.x = 2.f*(c2.x - c0.x); rc.y = 2.f*(c2.y - c0.y); \
        } else if (w == 62) { \
            ra.x = a1.x - a0.x; ra.y = a1.y - a0.y; \
            rb.x = b1.x - b0.x; rb.y = b1.y - b0.y; \
            rc.x = c1.x - c0.x; rc.y = c1.y - c0.y; \
        } else { \
            ra.x = 0.f; ra.y = 0.f; rb = ra; rc = ra; \
        } \
        acc[J] = pk_min_f16(acc[J], pk_min_f16(pk_min_f16(mm2(ra), mm2(rb)), mm2(rc))); \
        float gx = fmaf(0.114f, gelu_fast(rc.x), fmaf(0.587f, gelu_fast(rb.x), 0.2989f * gelu_fast(ra.x))); \
        float gy = fmaf(0.114f, gelu_fast(rc.y), fmaf(0.587f, gelu_fast(rb.y), 0.2989f * gelu_fast(ra.y))); \
        unsigned bx = q8(gx, qs), by = q8(gy, qs); \
        if ((w & 1) == 0) hp = bx | (by << 8); \
        else              gsr[w >> 1] = hp | (bx << 16) | (by << 24); \
        a0 = a1; a1 = a2; a2 = a3; a3 = a4; a4 = pa; \
        b0 = b1; b1 = b2; b2 = b3; b3 = b4; b4 = pb; \
        c0 = c1; c1 = c2; c2 = c3; c3 = c4; c4 = pc; \
        if (w <= 57) { pa = *(const float2*)xa; pb = *(const float2*)xb; pc = *(const float2*)xc; \
                       xa += HW; xb += HW; xc += HW; } \
    }

    #define FLUSH(J, T) { unsigned v = acc[J]; \
        v = pk_min_f16(v, (unsigned)__shfl_xor((int)v, 32, 64)); \
        v = pk_min_f16(v, (unsigned)__shfl_xor((int)v, 16, 64)); \
        v = pk_min_f16(v, (unsigned)__shfl_xor((int)v,  8, 64)); \
        v = pk_min_f16(v, (unsigned)__shfl_xor((int)v,  4, 64)); \
        v = pk_min_f16(v, (unsigned)__shfl_xor((int)v,  2, 64)); \
        v = pk_min_f16(v, (unsigned)__shfl_xor((int)v,  1, 64)); \
        if (lane == (T)) keep = v; }

    #pragma unroll
    for (int g = 0; g < 8; ++g) {
        #pragma unroll
        for (int j = 0; j < 8; ++j) acc[j] = 0x7BFF7BFFu;
        #pragma unroll
        for (int j = 0; j < 8; ++j) STEP(g, j)
        #pragma unroll
        for (int j = 0; j < 8; ++j) FLUSH(j, g * 8 + j)
    }
    #undef STEP
    #undef FLUSH

    {   // lane L holds f16 (min re, min -re) for window t=L (its wave's reduction)
        union { unsigned u; _Float16 h[2]; } cv; cv.u = keep;
        atomicMin(&smin[lane], encf((float)cv.h[0]));   // min re
        atomicMin(&smax[lane], encf((float)cv.h[1]));   // min(-re) == -(max re)
    }
    __syncthreads();
    if (tid < TT)            atomicMin(&gmm[tid], smin[tid]);
    else if (tid < 2 * TT)   atomicMin(&gmm[tid], smax[tid - TT]);

    // ---- grid barrier (all NBLK blocks co-resident; guarded at launch) ----
    __syncthreads();                        // drains vmcnt -> this block's atomics complete
    if (tid == 0) {
        __hip_atomic_fetch_add(cnt, 1u, __ATOMIC_RELEASE, __HIP_MEMORY_SCOPE_AGENT);
        while (__hip_atomic_load(cnt, __ATOMIC_ACQUIRE, __HIP_MEMORY_SCOPE_AGENT) < NBLK)
            __builtin_amdgcn_s_sleep(2);
    }
    __syncthreads();

    // ---- Phase C ----
    if (tid < TT) {
        float rmin =  decf(__hip_atomic_load(&gmm[tid],      __ATOMIC_RELAXED, __HIP_MEMORY_SCOPE_AGENT));
        float rmax = -decf(__hip_atomic_load(&gmm[TT + tid], __ATOMIC_RELAXED, __HIP_MEMORY_SCOPE_AGENT));
        float g0 = gelu_erf(rmin), g1 = gelu_erf(rmax);
        float gmaxv = fmaxf(g0, g1);
        float gminv;
        if (rmin >= XSTAR)      gminv = g0;
        else if (rmax <= XSTAR) gminv = g1;
        else                    gminv = fminf(gelu_erf(XSTAR), fminf(g0, g1));
        float mx = gmaxv - gminv;
        float inv = fast_rcp((mx != 0.f) ? mx : 1e-5f);
        sA[tid] = inv;
        sB[tid] = -gminv * SUMW * inv;
    }
    __syncthreads();

    float* op = out + (size_t)b * (68 * (size_t)HW) + hw;
    const float2 z2 = make_float2(0.f, 0.f);
    *(float2*)op = z2;
    *(float2*)(op + HW) = z2;
    *(float2*)(op + 2 * (size_t)HW) = z2;
    *(float2*)(op + 3 * (size_t)HW) = z2;
    op += 4 * (size_t)HW;
    #pragma unroll
    for (int i = 0; i < 32; ++i) {
        const int t0 = 2 * i, t1 = 2 * i + 1;
        const float iq0 = (t0 < 60) ? 0.125f : (t0 == 60 ? 0.08838835f : 0.02795085f);   // t0 ∈ {even} -> 60 or 62
        const float iq1 = (t1 < 60) ? 0.125f : (t1 == 61 ? 0.05590170f : 0.125f);        // t1 odd -> 61 or 63
        unsigned v = gsr[i];
        float A0 = sA[t0], B0 = sB[t0], A1 = sA[t1], B1 = sB[t1];
        float2 o0, o1;
        o0.x = fmaf(((float)(int)( v        & 255u) - 8.f) * iq0, A0, B0);
        o0.y = fmaf(((float)(int)((v >>  8) & 255u) - 8.f) * iq0, A0, B0);
        o1.x = fmaf(((float)(int)((v >> 16) & 255u) - 8.f) * iq1, A1, B1);
        o1.y = fmaf(((float)(int)( v >> 24        ) - 8.f) * iq1, A1, B1);
        *(float2*)(op + (size_t)t0 * HW) = o0;
        *(float2*)(op + (size_t)t1 * HW) = o1;
    }
}

// ===================== FALLBACK: round-11 two/three-kernel path =====================
template<bool WGS>
__global__ __launch_bounds__(256, 4) void k_pass1(const float* __restrict__ x,
                                                  unsigned* __restrict__ part,
                                                  unsigned* __restrict__ gs) {
    __shared__ unsigned smin[TT], smax[TT];
    const int tid = threadIdx.x;
    if (tid < TT) smin[tid] = 0xFFFFFFFFu;
    else if (tid < 2 * TT) smax[tid - TT] = 0u;
    __syncthreads();

    const int bid = blockIdx.x;
    const int b   = bid / 98;
    const int hwb = bid - b * 98;
    const int hw  = (hwb * 256 + tid) * 2;
    const float* xa = x + ((size_t)(b * 3 + 0) * TT) * (size_t)HW + hw;
    const float* xb = x + ((size_t)(b * 3 + 1) * TT) * (size_t)HW + hw;
    const float* xc = x + ((size_t)(b * 3 + 2) * TT) * (size_t)HW + hw;
    unsigned* gp = gs + ((size_t)b * TT) * (size_t)HW2 + (hwb * 256 + tid);

    const int lane = tid & 63;
    unsigned keep = 0x7BFF7BFFu;

    float2 a0 = *(const float2*)xa, b0 = *(const float2*)xb, c0 = *(const float2*)xc;
    float2 a1 = *(const float2*)(xa + HW), b1 = *(const float2*)(xb + HW), c1 = *(const float2*)(xc + HW);
    float2 a2 = *(const float2*)(xa + 2*(size_t)HW), b2 = *(const float2*)(xb + 2*(size_t)HW), c2 = *(const float2*)(xc + 2*(size_t)HW);
    float2 a3 = *(const float2*)(xa + 3*(size_t)HW), b3 = *(const float2*)(xb + 3*(size_t)HW), c3 = *(const float2*)(xc + 3*(size_t)HW);
    float2 a4 = *(const float2*)(xa + 4*(size_t)HW), b4 = *(const float2*)(xb + 4*(size_t)HW), c4 = *(const float2*)(xc + 4*(size_t)HW);
    float2 pa = *(const float2*)(xa + 5*(size_t)HW), pb = *(const float2*)(xb + 5*(size_t)HW), pc = *(const float2*)(xc + 5*(size_t)HW);
    xa += 6 * (size_t)HW; xb += 6 * (size_t)HW; xc += 6 * (size_t)HW;

    unsigned acc[8];

    #define STEP_FULL(J) { \
        float2 ra = re_full2(a0, a1, a3, a4); \
        float2 rb = re_full2(b0, b1, b3, b4); \
        float2 rc = re_full2(c0, c1, c3, c4); \
        acc[J] = pk_min_f16(acc[J], pk_min_f16(pk_min_f16(mm2(ra), mm2(rb)), mm2(rc))); \
        if constexpr (WGS) { \
            float gx = fmaf(0.114f, gelu_fast(rc.x), fmaf(0.587f, gelu_fast(rb.x), 0.2989f * gelu_fast(ra.x))); \
            float gy = fmaf(0.114f, gelu_fast(rc.y), fmaf(0.587f, gelu_fast(rb.y), 0.2989f * gelu_fast(ra.y))); \
            *gp = pack2(gx, gy); \
        } \
        gp += HW2; \
        a0 = a1; a1 = a2; a2 = a3; a3 = a4; a4 = pa; \
        b0 = b1; b1 = b2; b2 = b3; b3 = b4; b4 = pb; \
        c0 = c1; c1 = c2; c2 = c3; c3 = c4; c4 = pc; }

    #define PREFETCH() { pa = *(const float2*)xa; pb = *(const float2*)xb; pc = *(const float2*)xc; \
                         xa += HW; xb += HW; xc += HW; }

    #define FLUSH(J, T) { unsigned v = acc[J]; \
        v = pk_min_f16(v, (unsigned)__shfl_xor((int)v, 32, 64)); \
        v = pk_min_f16(v, (unsigned)__shfl_xor((int)v, 16, 64)); \
        v = pk_min_f16(v, (unsigned)__shfl_xor((int)v,  8, 64)); \
        v = pk_min_f16(v, (unsigned)__shfl_xor((int)v,  4, 64)); \
        v = pk_min_f16(v, (unsigned)__shfl_xor((int)v,  2, 64)); \
        v = pk_min_f16(v, (unsigned)__shfl_xor((int)v,  1, 64)); \
        if (lane == (T)) keep = v; }

    for (int g = 0; g < 7; ++g) {
        #pragma unroll
        for (int j = 0; j < 8; ++j) acc[j] = 0x7BFF7BFFu;
        #pragma unroll
        for (int j = 0; j < 8; ++j) { STEP_FULL(j) PREFETCH() }
        #pragma unroll
        for (int j = 0; j < 8; ++j) FLUSH(j, g * 8 + j)
    }
    {
        #pragma unroll
        for (int j = 0; j < 8; ++j) acc[j] = 0x7BFF7BFFu;
        STEP_FULL(0) PREFETCH()
        STEP_FULL(1) PREFETCH()
        STEP_FULL(2)
        STEP_FULL(3)
        {
            float2 ra, rb, rc;
            ra.x = fmaf(3.f, a3.x - a0.x, a2.x - a1.x); ra.y = fmaf(3.f, a3.y - a0.y, a2.y - a1.y);
            rb.x = fmaf(3.f, b3.x - b0.x, b2.x - b1.x); rb.y = fmaf(3.f, b3.y - b0.y, b2.y - b1.y);
            rc.x = fmaf(3.f, c3.x - c0.x, c2.x - c1.x); rc.y = fmaf(3.f, c3.y - c0.y, c2.y - c1.y);
            acc[4] = pk_min_f16(acc[4], pk_min_f16(pk_min_f16(mm2(ra), mm2(rb)), mm2(rc)));
            if constexpr (WGS) {
                float gx = fmaf(0.114f, gelu_fast(rc.x), fmaf(0.587f, gelu_fast(rb.x), 0.2989f * gelu_fast(ra.x)));
                float gy = fmaf(0.114f, gelu_fast(rc.y), fmaf(0.587f, gelu_fast(rb.y), 0.2989f * gelu_fast(ra.y)));
                *gp = pack2(gx, gy);
            }
            gp += HW2;
            a0 = a1; a1 = a2; a2 = a3;
            b0 = b1; b1 = b2; b2 = b3;
            c0 = c1; c1 = c2; c2 = c3;
        }
        {
            float2 ra, rb, rc;
            ra.x = 2.f*(a2.x-a0.x); ra.y = 2.f*(a2.y-a0.y);
            rb.x = 2.f*(b2.x-b0.x); rb.y = 2.f*(b2.y-b0.y);
            rc.x = 2.f*(c2.x-c0.x); rc.y = 2.f*(c2.y-c0.y);
            acc[5] = pk_min_f16(acc[5], pk_min_f16(pk_min_f16(mm2(ra), mm2(rb)), mm2(rc)));
            if constexpr (WGS) {
                float gx = fmaf(0.114f, gelu_fast(rc.x), fmaf(0.587f, gelu_fast(rb.x), 0.2989f * gelu_fast(ra.x)));
                float gy = fmaf(0.114f, gelu_fast(rc.y), fmaf(0.587f, gelu_fast(rb.y), 0.2989f * gelu_fast(ra.y)));
                *gp = pack2(gx, gy);
            }
            gp += HW2;
            a0 = a1; a1 = a2;
            b0 = b1; b1 = b2;
            c0 = c1; c1 = c2;
        }
        {
            float2 ra, rb, rc;
            ra.x = a1.x-a0.x; ra.y = a1.y-a0.y;
            rb.x = b1.x-b0.x; rb.y = b1.y-b0.y;
            rc.x = c1.x-c0.x; rc.y = c1.y-c0.y;
            acc[6] = pk_min_f16(acc[6], pk_min_f16(pk_min_f16(mm2(ra), mm2(rb)), mm2(rc)));
            if constexpr (WGS) {
                float gx = fmaf(0.114f, gelu_fast(rc.x), fmaf(0.587f, gelu_fast(rb.x), 0.2989f * gelu_fast(ra.x)));
                float gy = fmaf(0.114f, gelu_fast(rc.y), fmaf(0.587f, gelu_fast(rb.y), 0.2989f * gelu_fast(ra.y)));
                *gp = pack2(gx, gy);
            }
            gp += HW2;
        }
        {
            acc[7] = pk_min_f16(acc[7], 0u);
            if constexpr (WGS) *gp = 0u;
        }
        #pragma unroll
        for (int j = 0; j < 8; ++j) FLUSH(j, 56 + j)
    }
    #undef STEP_FULL
    #undef PREFETCH
    #undef FLUSH

    {
        union { unsigned u; _Float16 h[2]; } cv; cv.u = keep;
        const float amin = (float)cv.h[0];
        const float amax = -(float)cv.h[1];
        const float g0 = gelu_erf(amin), g1 = gelu_erf(amax);
        const float gmax = fmaxf(g0, g1);
        float gmin;
        if (amin >= XSTAR)      gmin = g0;
        else if (amax <= XSTAR) gmin = g1;
        else                    gmin = fminf(gelu_erf(XSTAR), fminf(g0, g1));
        atomicMin(&smin[lane], encf(gmin));
        atomicMax(&smax[lane], encf(gmax));
    }
    __syncthreads();
    if (tid < TT)            part[(size_t)tid * NBP + bid] = smin[tid];
    else if (tid < 2 * TT)   part[(size_t)tid * NBP + bid] = smax[tid - TT];
}

__device__ __forceinline__ void reduce_part(const unsigned* __restrict__ part, int tm,
                                            int tid, float& A, float& Bv) {
    __shared__ unsigned rm[4], rx[4];
    const unsigned* pm = part + (size_t)tm * NBP;
    const unsigned* px = part + (size_t)(TT + tm) * NBP;
    unsigned vmn = 0xFFFFFFFFu, vmx = 0u;
    for (int i = tid; i < NBP; i += 256) {
        vmn = min(vmn, pm[i]);
        vmx = max(vmx, px[i]);
    }
    #pragma unroll
    for (int off = 32; off; off >>= 1) {
        vmn = min(vmn, (unsigned)__shfl_xor((int)vmn, off, 64));
        vmx = max(vmx, (unsigned)__shfl_xor((int)vmx, off, 64));
    }
    if ((tid & 63) == 0) { rm[tid >> 6] = vmn; rx[tid >> 6] = vmx; }
    __syncthreads();
    vmn = min(min(rm[0], rm[1]), min(rm[2], rm[3]));
    vmx = max(max(rx[0], rx[1]), max(rx[2], rx[3]));
    float mn = decf(vmn);
    float mx = decf(vmx) - mn;
    float inv = fast_rcp((mx != 0.f) ? mx : 1e-5f);
    A  = inv;
    Bv = -mn * SUMW * inv;
}

__global__ __launch_bounds__(256) void k_pass3(const unsigned* __restrict__ gs,
                                               const unsigned* __restrict__ part,
                                               float* __restrict__ out) {
    const int bid = blockIdx.x;
    const int b   = bid / 476;
    const int r   = bid - b * 476;
    const int t   = r / 7;
    const int seg = r - t * 7;
    const int tid = threadIdx.x;
    const int base4 = seg * 1792 + tid;
    float4* op = (float4*)out + ((size_t)b * 68 + t) * HW4 + base4;

    if (t < 4) {
        float4 z = make_float4(0.f, 0.f, 0.f, 0.f);
        #pragma unroll
        for (int k = 0; k < 7; ++k) op[k * 256] = z;
        return;
    }
    const int tm = t - 4;
    float A, Bv;
    reduce_part(part, tm, tid, A, Bv);

    const uint2* gpp = (const uint2*)gs + ((size_t)b * TT + tm) * HW4 + base4;
    #pragma unroll
    for (int k = 0; k < 7; ++k) {
        uint2 v = gpp[k * 256];
        union { unsigned u; _Float16 h[2]; } lo, hi; lo.u = v.x; hi.u = v.y;
        float4 o;
        o.x = fmaf((float)lo.h[0], A, Bv);
        o.y = fmaf((float)lo.h[1], A, Bv);
        o.z = fmaf((float)hi.h[0], A, Bv);
        o.w = fmaf((float)hi.h[1], A, Bv);
        op[k * 256] = o;
    }
}

extern "C" void kernel_launch(void* const* d_in, const int* in_sizes, int n_in,
                              void* d_out, int out_size, void* d_ws, size_t ws_size,
                              hipStream_t stream) {
    const float* x = (const float*)d_in[0];
    float* out = (float*)d_out;
    // ws: [0,512): gmm (128 u32, min-encoded both rows); [512,516): cnt;
    //     [4096, +401408): part (fallback); then gs (fallback, ~51.4MB)
    unsigned* gmm = (unsigned*)d_ws;
    unsigned* cnt = (unsigned*)((char*)d_ws + 512);
    unsigned* part = (unsigned*)((char*)d_ws + 4096);
    const size_t part_bytes = (size_t)2 * TT * NBP * 4;
    unsigned* gs = (unsigned*)((char*)d_ws + 4096 + part_bytes);
    const size_t need_fb = 4096 + part_bytes + (size_t)8 * TT * (size_t)HW2 * 4;

    int dev = 0;
    (void)hipGetDevice(&dev);
    int ncu = 0;
    (void)hipDeviceGetAttribute(&ncu, hipDeviceAttributeMultiprocessorCount, dev);
    int maxb = 0;
    (void)hipOccupancyMaxActiveBlocksPerMultiprocessor(&maxb, k_fused, 256, 0);

    if ((long long)maxb * (long long)ncu >= NBLK) {
        hipMemsetAsync(gmm, 0xFF, 2 * TT * sizeof(unsigned), stream);
        hipMemsetAsync(cnt, 0, sizeof(unsigned), stream);
        k_fused<<<NBLK, 256, 0, stream>>>(x, gmm, cnt, out);
    } else if (ws_size >= need_fb) {
        k_pass1<true><<<NBP, 256, 0, stream>>>(x, part, gs);
        k_pass3<<<3808, 256, 0, stream>>>(gs, part, out);
    }
}